// Round 1
// baseline (2037.191 us; speedup 1.0000x reference)
//
#include <hip/hip_runtime.h>

#define Bb 8
#define Nn 2500
#define Ee 100
#define Ff 50
#define Yy 8922
#define Kk 9
#define TY 4   // y-rows per block in attention kernel (1 wave per row)

// ---------------------------------------------------------------------------
// Kernel 1: embedding lookup + conv1d (SAME, K=9) + tanh
// writes h[b][n][f] and h_t[b][f][n]
// ---------------------------------------------------------------------------
__global__ __launch_bounds__(256)
void conv_kernel(const int* __restrict__ x, const float* __restrict__ embW,
                 const float* __restrict__ convW, const float* __restrict__ convB,
                 float* __restrict__ h, float* __restrict__ h_t)
{
    __shared__ __align__(16) float emb_s[72 * 101];   // 72 rows (64 + 8 halo), pad 101
    __shared__ __align__(16) float w_s[100 * 64];     // [e][4 groups x 16 slots]

    const int b  = blockIdx.y;
    const int n0 = blockIdx.x * 64;
    const int t  = threadIdx.x;

    // stage embedding rows n0-4 .. n0+67 (zero outside [0,N))
    for (int idx = t; idx < 72 * Ee; idx += 256) {
        int r = idx / Ee, c = idx - r * Ee;
        int n = n0 - 4 + r;
        float v = 0.0f;
        if (n >= 0 && n < Nn) v = embW[(size_t)x[b * Nn + n] * Ee + c];
        emb_s[r * 101 + c] = v;
    }

    const int nl = t & 63;   // n within tile
    const int g  = t >> 6;   // f-group: f = 13*g + j
    float acc[13];
#pragma unroll
    for (int j = 0; j < 13; ++j) acc[j] = 0.0f;

    for (int k = 0; k < Kk; ++k) {
        __syncthreads();
        // stage conv_w[:, :, k] as w_s[e*64 + g*16 + j], zero-padded slots
        for (int idx = t; idx < 100 * 64; idx += 256) {
            int e = idx >> 6, slot = idx & 63;
            int g2 = slot >> 4, j2 = slot & 15;
            int f2 = g2 * 13 + j2;
            float v = 0.0f;
            if (j2 < 13 && f2 < Ff) v = convW[(f2 * Ee + e) * Kk + k];
            w_s[idx] = v;
        }
        __syncthreads();
        const float* er    = &emb_s[(nl + k) * 101];
        const float* wbase = &w_s[g * 16];
        for (int e = 0; e < Ee; ++e) {
            float ev = er[e];
            const float* wr = wbase + e * 64;
            float4 w0 = *(const float4*)(wr);
            float4 w1 = *(const float4*)(wr + 4);
            float4 w2 = *(const float4*)(wr + 8);
            float  wc = wr[12];
            acc[0]  += ev * w0.x; acc[1]  += ev * w0.y; acc[2]  += ev * w0.z; acc[3]  += ev * w0.w;
            acc[4]  += ev * w1.x; acc[5]  += ev * w1.y; acc[6]  += ev * w1.z; acc[7]  += ev * w1.w;
            acc[8]  += ev * w2.x; acc[9]  += ev * w2.y; acc[10] += ev * w2.z; acc[11] += ev * w2.w;
            acc[12] += ev * wc;
        }
    }

    const int n = n0 + nl;
    if (n < Nn) {
#pragma unroll
        for (int j = 0; j < 13; ++j) {
            int f = g * 13 + j;
            if (f < Ff) {
                float v = tanhf(acc[j] + convB[f]);
                h  [((size_t)b * Nn + n) * Ff + f] = v;
                h_t[((size_t)b * Ff + f) * Nn + n] = v;
            }
        }
    }
}

// ---------------------------------------------------------------------------
// Kernel 2: per-label attention: scores -> softmax (alpha out) -> pool -> yhat
// block: (y-tile of TY rows, b); 256 threads = TY waves, 1 wave per y-row
// ---------------------------------------------------------------------------
__global__ __launch_bounds__(256)
void attn_kernel(const float* __restrict__ h, const float* __restrict__ h_t,
                 const float* __restrict__ U_w, const float* __restrict__ fin,
                 const float* __restrict__ finb, float* __restrict__ out)
{
    __shared__ __align__(16) float sc[TY * Nn];          // 40 KB score/alpha rows
    __shared__ __align__(16) float U_s[Ff * TY];         // [f][ty]
    __shared__ __align__(16) float fin_s[TY * 64];       // [ty][f(pad 64)]
    __shared__ __align__(16) float m_buf[TY * TY * 64];  // [wave][ty][f(pad 64)]
    __shared__ float bias_s[TY];

    const int b  = blockIdx.y;
    const int y0 = blockIdx.x * TY;
    const int t  = threadIdx.x;

    for (int idx = t; idx < Ff * TY; idx += 256) {
        int f = idx >> 2, ty = idx & 3;
        int y = y0 + ty;
        U_s[idx] = (y < Yy) ? U_w[y * Ff + f] : 0.0f;
    }
    for (int idx = t; idx < TY * 64; idx += 256) {
        int ty = idx >> 6, f = idx & 63;
        int y = y0 + ty;
        fin_s[idx] = (f < Ff && y < Yy) ? fin[y * Ff + f] : 0.0f;
    }
    if (t < TY) bias_s[t] = (y0 + t < Yy) ? finb[y0 + t] : 0.0f;
    __syncthreads();

    // ---- Phase 1: scores[ty][n] = sum_f h[b,n,f] * U[y0+ty,f] ----
    const float* hb = h_t + (size_t)b * Ff * Nn;
    for (int q = t; q < Nn / 4; q += 256) {
        const int n4 = q * 4;
        float4 a0 = make_float4(0.f, 0.f, 0.f, 0.f), a1 = a0, a2 = a0, a3 = a0;
        const float* hp = hb + n4;
        for (int f = 0; f < Ff; ++f) {
            float4 hv = *(const float4*)(hp + (size_t)f * Nn);
            float4 uv = *(const float4*)(&U_s[f * 4]);
            a0.x += hv.x * uv.x; a0.y += hv.y * uv.x; a0.z += hv.z * uv.x; a0.w += hv.w * uv.x;
            a1.x += hv.x * uv.y; a1.y += hv.y * uv.y; a1.z += hv.z * uv.y; a1.w += hv.w * uv.y;
            a2.x += hv.x * uv.z; a2.y += hv.y * uv.z; a2.z += hv.z * uv.z; a2.w += hv.w * uv.z;
            a3.x += hv.x * uv.w; a3.y += hv.y * uv.w; a3.z += hv.z * uv.w; a3.w += hv.w * uv.w;
        }
        *(float4*)&sc[0 * Nn + n4] = a0;
        *(float4*)&sc[1 * Nn + n4] = a1;
        *(float4*)&sc[2 * Nn + n4] = a2;
        *(float4*)&sc[3 * Nn + n4] = a3;
    }
    __syncthreads();

    // ---- Phase 2: softmax per row (wave w owns row ty=w), write alpha ----
    const int w = t >> 6;
    const int l = t & 63;
    {
        float M = -3.0e38f;
        for (int n = l; n < Nn; n += 64) M = fmaxf(M, sc[w * Nn + n]);
#pragma unroll
        for (int o = 32; o > 0; o >>= 1) M = fmaxf(M, __shfl_xor(M, o));
        float S = 0.0f;
        for (int n = l; n < Nn; n += 64) S += __expf(sc[w * Nn + n] - M);
#pragma unroll
        for (int o = 32; o > 0; o >>= 1) S += __shfl_xor(S, o);
        const float inv = 1.0f / S;
        const int y = y0 + w;
        if (y < Yy) {
            float* ag = out + (size_t)Bb * Yy + 1 + ((size_t)b * Yy + y) * (size_t)Nn;
            for (int n = l; n < Nn; n += 64) {
                float a = __expf(sc[w * Nn + n] - M) * inv;
                sc[w * Nn + n] = a;
                ag[n] = a;
            }
        } else {
            for (int n = l; n < Nn; n += 64)
                sc[w * Nn + n] = __expf(sc[w * Nn + n] - M) * inv;
        }
    }
    __syncthreads();

    // ---- Phase 3: m[ty][f] = sum_n alpha[ty][n] * h[b,n,f]; lane = f ----
    const float* hbn = h + (size_t)b * Nn * Ff;
    float m0 = 0.f, m1 = 0.f, m2 = 0.f, m3 = 0.f;
    if (l < Ff) {
        for (int qi = w; qi < Nn / 4; qi += TY) {
            const int n4 = qi * 4;
            const float* hp = hbn + (size_t)n4 * Ff + l;
            float h0 = hp[0], h1 = hp[Ff], h2 = hp[2 * Ff], h3 = hp[3 * Ff];
            float4 av;
            av = *(const float4*)&sc[0 * Nn + n4]; m0 += av.x * h0 + av.y * h1 + av.z * h2 + av.w * h3;
            av = *(const float4*)&sc[1 * Nn + n4]; m1 += av.x * h0 + av.y * h1 + av.z * h2 + av.w * h3;
            av = *(const float4*)&sc[2 * Nn + n4]; m2 += av.x * h0 + av.y * h1 + av.z * h2 + av.w * h3;
            av = *(const float4*)&sc[3 * Nn + n4]; m3 += av.x * h0 + av.y * h1 + av.z * h2 + av.w * h3;
        }
    }
    m_buf[(w * TY + 0) * 64 + l] = m0;
    m_buf[(w * TY + 1) * 64 + l] = m1;
    m_buf[(w * TY + 2) * 64 + l] = m2;
    m_buf[(w * TY + 3) * 64 + l] = m3;
    __syncthreads();

    // ---- Phase 4: reduce partials, logits, sigmoid ----
    {
        const int ty = w;
        float s = 0.0f;
#pragma unroll
        for (int ww = 0; ww < TY; ++ww) s += m_buf[(ww * TY + ty) * 64 + l];
        float p = s * fin_s[ty * 64 + l];
#pragma unroll
        for (int o = 32; o > 0; o >>= 1) p += __shfl_xor(p, o);
        const int y = y0 + ty;
        if (l == 0 && y < Yy) {
            float logit = p + bias_s[ty];
            out[b * Yy + y] = 1.0f / (1.0f + __expf(-logit));
        }
    }
}

// ---------------------------------------------------------------------------
// Kernel 3: BCE loss (mean) over yhat (already in out[0..B*Y)) vs target
// ---------------------------------------------------------------------------
__global__ __launch_bounds__(1024)
void loss_kernel(const float* __restrict__ target, float* __restrict__ out)
{
    __shared__ float red[16];
    const int t = threadIdx.x;
    float acc = 0.0f;
    for (int i = t; i < Bb * Yy; i += 1024) {
        float p = out[i];
        p = fminf(fmaxf(p, 1e-7f), 1.0f - 1e-7f);
        float tg = target[i];
        acc += tg * logf(p) + (1.0f - tg) * log1pf(-p);
    }
#pragma unroll
    for (int o = 32; o > 0; o >>= 1) acc += __shfl_xor(acc, o);
    if ((t & 63) == 0) red[t >> 6] = acc;
    __syncthreads();
    if (t == 0) {
        float s = 0.0f;
#pragma unroll
        for (int i = 0; i < 16; ++i) s += red[i];
        out[Bb * Yy] = -s / (float)(Bb * Yy);
    }
}

// ---------------------------------------------------------------------------
extern "C" void kernel_launch(void* const* d_in, const int* in_sizes, int n_in,
                              void* d_out, int out_size, void* d_ws, size_t ws_size,
                              hipStream_t stream)
{
    const int*   x      = (const int*)  d_in[0];
    const float* target = (const float*)d_in[1];
    const float* embW   = (const float*)d_in[2];
    const float* convW  = (const float*)d_in[3];
    const float* convB  = (const float*)d_in[4];
    const float* U_w    = (const float*)d_in[5];
    const float* fin    = (const float*)d_in[6];
    const float* finb   = (const float*)d_in[7];
    float* out = (float*)d_out;
    float* h   = (float*)d_ws;                                    // 4 MB: h[b][n][f]
    float* h_t = (float*)((char*)d_ws + (size_t)4 * 1024 * 1024); // 4 MB: h_t[b][f][n]

    dim3 g1((Nn + 63) / 64, Bb);
    conv_kernel<<<g1, dim3(256), 0, stream>>>(x, embW, convW, convB, h, h_t);

    dim3 g2((Yy + TY - 1) / TY, Bb);
    attn_kernel<<<g2, dim3(256), 0, stream>>>(h, h_t, U_w, fin, finb, out);

    loss_kernel<<<dim3(1), dim3(1024), 0, stream>>>(target, out);
}